// Round 2
// baseline (870.824 us; speedup 1.0000x reference)
//
#include <hip/hip_runtime.h>

// ---------------------------------------------------------------------------
// TiLISTA: M=512, N=2048, B=8192, T=5 — i8 dual-plane GEMMs, fp32 x state.
//   x0 = mu0 * y @ A                      (fp32 in d_out)
//   for t=1..5:
//     r = x @ A^T - y        (fp32 in ws -> per-row i8 planes)
//     z = x - mu_t * (r @ A) (x read fp32 from d_out, z written in place)
//     x = shrink(z,beta,k)   (fp32 in d_out + i8 planes for next GEMM)
// GEMM operands: per-row q = q1*128 + q0 (|q|<=16256, ~15 bits of rowmax).
// 3 x mfma_i32_16x16x64_i8 per 64-K: a1b1->accH, a1b0+a0b1->accM;
// v = sA*sB*(accH*16384 + accM*128). Numerics: GEMM-input quant noise
// averages through A's unit-norm columns (~6e-6); x kept fp32 so direct
// storage error is 0. z error ~1e-5 = single tie-flip floor (R3-measured).
// Grid flat-swizzle: m-block = flat%64 -> same-m blocks share an XCD L2 (R6).
// R9: GEMM schedule rewrite (T2+T3+T4+T5): LDS double-buffer + prefetch-
//   before-compute, raw s_barrier + counted s_waitcnt vmcnt(L) (loads stay
//   in flight across barriers), XOR-swizzled tiles (source-side pre-swizzle,
//   read-side XOR), s_setprio around MFMA cluster. 72 -> <57 us per GEMM.
// R10: shrink rewrite. Was 57.6 us x6, VALUBusy 67%, occ 33% — serial-
//   latency bound in the 31-iter binary search (6-shfl butterfly chain per
//   iter). Now: 2 rows per wave, both searches interleaved, per-row counts
//   packed c0|c1<<16 -> ONE 6-shfl reduce serves both rows (2x ILP, half
//   the serial chains per row). Values held as abs-bits + 1-bit sign mask
//   (1 VGPR/row vs 32) so 2-row state fits ~100 VGPR. t=5 skips plane +
//   scale writes (nothing consumes them). Same search invariant, same
//   quant math (rn is sign-symmetric) -> bit-identical results.
// shrink = exact k-th-largest |z| via binary search on float bits.
// ---------------------------------------------------------------------------

typedef int int4v __attribute__((ext_vector_type(4)));

__device__ __forceinline__ void quant2(float v, float inv_s,
                                       signed char& q1, signed char& q0) {
    int q = __float2int_rn(v * inv_s);
    q = q > 16256 ? 16256 : (q < -16256 ? -16256 : q);
    int hi = (q + 64) >> 7;            // round-half-up -> [-127,127]
    q1 = (signed char)hi;
    q0 = (signed char)(q - (hi << 7)); // [-64,63]
}

__device__ __forceinline__ void gl_lds16(const signed char* g, signed char* lds) {
    __builtin_amdgcn_global_load_lds(
        (const __attribute__((address_space(1))) void*)g,
        (__attribute__((address_space(3))) void*)lds, 16, 0, 0);
}

// out[m][n] = epilogue( sum_k Aop[m][k]*Bop[k][n] ); Bop in B^T layout [n][k].
// EPI 0: outF = mu * v                  (x0; A=y planes, B=AT planes)
// EPI 1: outF = v - yF                  (r;  A=x planes, B=A planes)
// EPI 2: outF = Yaux - mu * v, in place (z;  A=r planes, B=AT planes, Yaux=x)
template<int NJ, int EPI>
__global__ __launch_bounds__(256, 2) void gemm_i8(
    const signed char* __restrict__ A1, const signed char* __restrict__ A0, int lda,
    const signed char* __restrict__ B1, const signed char* __restrict__ B0, int ldb,
    const float* __restrict__ sAv,   // per-row scale of A-operand
    const float* __restrict__ sBv,   // per-row scale of B-operand (per out col)
    const float* __restrict__ Yaux,  // EPI1: y fp32 ; EPI2: x fp32 (= outF)
    float* __restrict__ outF,
    const float* __restrict__ muPtr, int muIdx, int K, int ldOut)
{
    constexpr int BN = 32 * NJ;      // 128 (NJ=4) or 64 (NJ=2)
    // double-buffered tiles: NJ=4 -> 64 KiB total, NJ=2 -> 48 KiB
    __shared__ signed char As1[2][128 * 64];
    __shared__ signed char As0[2][128 * 64];
    __shared__ signed char Bs1[2][BN * 64];
    __shared__ signed char Bs0[2][BN * 64];

    const int tid  = threadIdx.x;
    const int wid  = tid >> 6;
    const int lane = tid & 63;
    const int quad = lane >> 4;
    const int l16  = lane & 15;
    const int waveM = (wid >> 1) * 64;
    const int waveN = (wid & 1) * (16 * NJ);
    const int swz   = (l16 >> 1) & 3;          // read-side XOR (rows: base%16==0)

    const int flat  = blockIdx.x + gridDim.x * blockIdx.y;
    const int mBase = (flat & 63) * 128;
    const int nBase = (flat >> 6) * BN;

    int4v accH[4][NJ] = {};
    int4v accM[4][NJ] = {};

    // Stage one 64-K tile into buffer b. LDS dest linear (global_load_lds
    // requirement); the global SOURCE chunk is XOR-swizzled so that the
    // ds_read below, applying the same XOR, sees logical chunk order.
    auto stage = [&](int b, int k0) {
        #pragma unroll
        for (int rr = 0; rr < 2; ++rr) {
            int c   = rr * 256 + tid;          // 16B chunk id, 0..511
            int row = c >> 2;
            int js  = (c & 3) ^ ((row >> 1) & 3);
            size_t ga = (size_t)(mBase + row) * lda + k0 + js * 16;
            size_t doff = (size_t)((rr * 256 + wid * 64) * 16);
            gl_lds16(A1 + ga, As1[b] + doff);
            gl_lds16(A0 + ga, As0[b] + doff);
        }
        // chunk count = BN*64B / 16B = BN*4; iterations = BN*4/256 = BN/64
        #pragma unroll
        for (int rr = 0; rr < BN / 64; ++rr) {
            int c   = rr * 256 + tid;
            int row = c >> 2;
            int js  = (c & 3) ^ ((row >> 1) & 3);
            size_t gb = (size_t)(nBase + row) * ldb + k0 + js * 16;
            size_t doff = (size_t)((rr * 256 + wid * 64) * 16);
            gl_lds16(B1 + gb, Bs1[b] + doff);
            gl_lds16(B0 + gb, Bs0[b] + doff);
        }
    };

    const int KT = K >> 6;
    stage(0, 0);

    for (int kt = 0; kt < KT; ++kt) {
        const int cur = kt & 1;
        if (kt + 1 < KT) {
            stage(cur ^ 1, (kt + 1) << 6);
            // wait tile-kt's loads only; tile-(kt+1)'s L loads stay in flight
            if constexpr (NJ == 4) asm volatile("s_waitcnt vmcnt(8)" ::: "memory");
            else                   asm volatile("s_waitcnt vmcnt(6)" ::: "memory");
        } else {
            asm volatile("s_waitcnt vmcnt(0)" ::: "memory");
        }
        __builtin_amdgcn_s_barrier();          // raw: no vmcnt drain

        int4v a1[4], a0[4], b1[NJ], b0[NJ];
        #pragma unroll
        for (int i = 0; i < 4; ++i) {
            int off = (waveM + i * 16 + l16) * 64 + ((quad ^ swz) * 16);
            a1[i] = *(const int4v*)(&As1[cur][off]);
            a0[i] = *(const int4v*)(&As0[cur][off]);
        }
        #pragma unroll
        for (int j = 0; j < NJ; ++j) {
            int off = (waveN + j * 16 + l16) * 64 + ((quad ^ swz) * 16);
            b1[j] = *(const int4v*)(&Bs1[cur][off]);
            b0[j] = *(const int4v*)(&Bs0[cur][off]);
        }
        __builtin_amdgcn_s_setprio(1);
        #pragma unroll
        for (int i = 0; i < 4; ++i)
            #pragma unroll
            for (int j = 0; j < NJ; ++j) {
                accH[i][j] = __builtin_amdgcn_mfma_i32_16x16x64_i8(a1[i], b1[j], accH[i][j], 0, 0, 0);
                accM[i][j] = __builtin_amdgcn_mfma_i32_16x16x64_i8(a1[i], b0[j], accM[i][j], 0, 0, 0);
                accM[i][j] = __builtin_amdgcn_mfma_i32_16x16x64_i8(a0[i], b1[j], accM[i][j], 0, 0, 0);
            }
        __builtin_amdgcn_s_setprio(0);
        __builtin_amdgcn_s_barrier();          // reads of buf[cur] done before
                                               // next iter's stage overwrites it
    }

    const float mu = muPtr[muIdx];
    #pragma unroll
    for (int i = 0; i < 4; ++i) {
        #pragma unroll
        for (int j = 0; j < NJ; ++j) {
            const int gr0 = mBase + waveM + i * 16 + quad * 4;
            const int gc  = nBase + waveN + j * 16 + l16;
            const float sB = sBv[gc];
            #pragma unroll
            for (int r2 = 0; r2 < 4; ++r2) {
                const int    gr  = gr0 + r2;
                const size_t idx = (size_t)gr * ldOut + gc;
                const float  sA  = sAv[gr];
                float v = sA * sB * ((float)accH[i][j][r2] * 16384.f
                                   + (float)accM[i][j][r2] * 128.f);
                if constexpr (EPI == 0)      outF[idx] = mu * v;
                else if constexpr (EPI == 1) outF[idx] = v - Yaux[idx];
                else                         outF[idx] = Yaux[idx] - mu * v;
            }
        }
    }
}

// per-row quantization of a fp32 matrix to i8 dual planes + row scale
template<int COLS>
__global__ __launch_bounds__(256) void rowquant_kernel(
    const float* __restrict__ src,
    signed char* __restrict__ q1, signed char* __restrict__ q0,
    float* __restrict__ scale)
{
    const int wid  = threadIdx.x >> 6;
    const int lane = threadIdx.x & 63;
    const long long row = (long long)blockIdx.x * 4 + wid;
    constexpr int EP = COLS / 256;   // float4 per lane
    const float* s = src + row * COLS;

    float v[EP * 4];
    #pragma unroll
    for (int c = 0; c < EP; ++c) {
        float4 f = ((const float4*)s)[c * 64 + lane];
        v[c * 4 + 0] = f.x; v[c * 4 + 1] = f.y; v[c * 4 + 2] = f.z; v[c * 4 + 3] = f.w;
    }
    float mx = 0.f;
    #pragma unroll
    for (int i = 0; i < EP * 4; ++i) mx = fmaxf(mx, fabsf(v[i]));
    #pragma unroll
    for (int off = 32; off >= 1; off >>= 1) mx = fmaxf(mx, __shfl_xor(mx, off, 64));
    mx = fmaxf(mx, 1e-20f);
    if (lane == 0) scale[row] = mx / 16256.f;
    const float inv = 16256.f / mx;

    #pragma unroll
    for (int c = 0; c < EP; ++c) {
        size_t col = (size_t)(c * 64 + lane) * 4;
        signed char h[4], l[4];
        #pragma unroll
        for (int e = 0; e < 4; ++e) quant2(v[c * 4 + e], inv, h[e], l[e]);
        *(char4*)(q1 + row * COLS + col) = *(char4*)h;
        *(char4*)(q0 + row * COLS + col) = *(char4*)l;
    }
}

// R10: one wave per TWO rows of z[.,2048]. Exact k-th-largest |z| hard/soft
// threshold (two interleaved binary searches sharing one packed shfl-reduce),
// per-row quantize x -> i8 planes + scale, optionally write x fp32.
// State per row: 32 abs-bit regs + one 32-bit sign mask.
__global__ __launch_bounds__(256) void shrink_kernel(
    float* __restrict__ z,
    signed char* __restrict__ X1, signed char* __restrict__ X0,
    float* __restrict__ sX,
    const float* __restrict__ betaPtr, int tIdx, int kSel,
    int writeF32, int writePlanes)
{
    const int wid  = threadIdx.x >> 6;
    const int lane = threadIdx.x & 63;
    const long long r0 = (long long)blockIdx.x * 8 + wid * 2;  // rows r0, r0+1
    float* z0 = z + r0 * 2048;
    float* z1 = z0 + 2048;

    unsigned a0[32], a1[32];
    unsigned s0 = 0, s1 = 0;
    #pragma unroll
    for (int c = 0; c < 8; ++c) {
        float4 f0 = ((const float4*)z0)[c * 64 + lane];
        float4 f1 = ((const float4*)z1)[c * 64 + lane];
        const float e0[4] = {f0.x, f0.y, f0.z, f0.w};
        const float e1[4] = {f1.x, f1.y, f1.z, f1.w};
        #pragma unroll
        for (int e = 0; e < 4; ++e) {
            unsigned b0 = __float_as_uint(e0[e]);
            unsigned b1 = __float_as_uint(e1[e]);
            s0 |= (b0 >> 31) << (c * 4 + e);
            s1 |= (b1 >> 31) << (c * 4 + e);
            a0[c * 4 + e] = b0 & 0x7FFFFFFFu;
            a1[c * 4 + e] = b1 & 0x7FFFFFFFu;
        }
    }

    if (kSel > 0) {
        const float beta = betaPtr[tIdx];
        // invariant: cnt(>=lo) >= k, cnt(>=hi) < k; integers -> exact k-th.
        unsigned lo0 = 0u, hi0 = 0x7F800000u;
        unsigned lo1 = 0u, hi1 = 0x7F800000u;
        for (int it = 0; it < 31; ++it) {
            const unsigned m0 = (lo0 + hi0) >> 1;
            const unsigned m1 = (lo1 + hi1) >> 1;
            int c0 = 0, c1 = 0;
            #pragma unroll
            for (int i = 0; i < 32; ++i) {
                c0 += (a0[i] >= m0) ? 1 : 0;
                c1 += (a1[i] >= m1) ? 1 : 0;
            }
            // per-row counts <= 2048: pack both rows, one butterfly for both
            int pk = c0 | (c1 << 16);
            #pragma unroll
            for (int off = 32; off >= 1; off >>= 1) pk += __shfl_xor(pk, off, 64);
            if ((pk & 0xFFFF) >= kSel) lo0 = m0; else hi0 = m0;
            if ((pk >> 16)    >= kSel) lo1 = m1; else hi1 = m1;
        }
        const unsigned thr0 = lo0, thr1 = lo1;
        #pragma unroll
        for (int i = 0; i < 32; ++i) {
            float af0 = __uint_as_float(a0[i]);
            float af1 = __uint_as_float(a1[i]);
            unsigned sf0 = __float_as_uint(fmaxf(af0 - beta, 0.f));
            unsigned sf1 = __float_as_uint(fmaxf(af1 - beta, 0.f));
            a0[i] = (a0[i] >= thr0) ? a0[i] : sf0;
            a1[i] = (a1[i] >= thr1) ? a1[i] : sf1;
        }
    }

    // row max over abs bits (non-negative floats: uint order == float order)
    unsigned mx0 = 0u, mx1 = 0u;
    #pragma unroll
    for (int i = 0; i < 32; ++i) {
        mx0 = a0[i] > mx0 ? a0[i] : mx0;
        mx1 = a1[i] > mx1 ? a1[i] : mx1;
    }
    #pragma unroll
    for (int off = 32; off >= 1; off >>= 1) {
        unsigned t0 = (unsigned)__shfl_xor((int)mx0, off, 64);
        unsigned t1 = (unsigned)__shfl_xor((int)mx1, off, 64);
        mx0 = t0 > mx0 ? t0 : mx0;
        mx1 = t1 > mx1 ? t1 : mx1;
    }
    const float fm0 = fmaxf(__uint_as_float(mx0), 1e-20f);
    const float fm1 = fmaxf(__uint_as_float(mx1), 1e-20f);
    if (writePlanes && lane == 0) {
        sX[r0]     = fm0 / 16256.f;
        sX[r0 + 1] = fm1 / 16256.f;
    }
    const float inv0 = 16256.f / fm0;
    const float inv1 = 16256.f / fm1;

    #pragma unroll
    for (int c = 0; c < 8; ++c) {
        const size_t col = (size_t)(c * 64 + lane) * 4;
        signed char h0[4], l0[4], h1[4], l1[4];
        float w0[4], w1[4];
        #pragma unroll
        for (int e = 0; e < 4; ++e) {
            const int i = c * 4 + e;
            const unsigned sg0 = (s0 >> i) & 1u;
            const unsigned sg1 = (s1 >> i) & 1u;
            const float av0 = __uint_as_float(a0[i]);
            const float av1 = __uint_as_float(a1[i]);
            w0[e] = __uint_as_float(a0[i] | (sg0 << 31));
            w1[e] = __uint_as_float(a1[i] | (sg1 << 31));
            // quantize abs, reapply sign: rn is sign-symmetric -> identical
            // to quantizing the signed value (plane split exact either way)
            int q0i = __float2int_rn(av0 * inv0);
            int q1i = __float2int_rn(av1 * inv1);
            q0i = q0i > 16256 ? 16256 : q0i;
            q1i = q1i > 16256 ? 16256 : q1i;
            q0i = sg0 ? -q0i : q0i;
            q1i = sg1 ? -q1i : q1i;
            int hi0b = (q0i + 64) >> 7;
            int hi1b = (q1i + 64) >> 7;
            h0[e] = (signed char)hi0b;  l0[e] = (signed char)(q0i - (hi0b << 7));
            h1[e] = (signed char)hi1b;  l1[e] = (signed char)(q1i - (hi1b << 7));
        }
        if (writePlanes) {
            *(char4*)(X1 + r0 * 2048 + col)       = *(char4*)h0;
            *(char4*)(X0 + r0 * 2048 + col)       = *(char4*)l0;
            *(char4*)(X1 + (r0 + 1) * 2048 + col) = *(char4*)h1;
            *(char4*)(X0 + (r0 + 1) * 2048 + col) = *(char4*)l1;
        }
        if (writeF32) {
            float4 f0, f1;
            f0.x = w0[0]; f0.y = w0[1]; f0.z = w0[2]; f0.w = w0[3];
            f1.x = w1[0]; f1.y = w1[1]; f1.z = w1[2]; f1.w = w1[3];
            ((float4*)z0)[c * 64 + lane] = f0;
            ((float4*)z1)[c * 64 + lane] = f1;
        }
    }
}

extern "C" void kernel_launch(void* const* d_in, const int* in_sizes, int n_in,
                              void* d_out, int out_size, void* d_ws, size_t ws_size,
                              hipStream_t stream)
{
    const float* y    = (const float*)d_in[0];   // [8192,512]
    const float* A    = (const float*)d_in[1];   // [512,2048]
    const float* W    = (const float*)d_in[2];   // [2048,512] == A^T
    const float* beta = (const float*)d_in[3];   // [6]
    const float* mu   = (const float*)d_in[4];   // [6]
    float* out = (float*)d_out;                  // x / z fp32, in place

    // workspace (~68 MB)
    signed char* A1q  = (signed char*)d_ws;          // [512][2048]
    signed char* A0q  = A1q  + 512 * 2048;
    signed char* AT1q = A0q  + 512 * 2048;           // [2048][512]
    signed char* AT0q = AT1q + 2048 * 512;
    signed char* y1q  = AT0q + 2048 * 512;           // [8192][512]
    signed char* y0q  = y1q  + 8192 * 512;
    signed char* x1q  = y0q  + 8192 * 512;           // [8192][2048]
    signed char* x0q  = x1q  + (size_t)8192 * 2048;
    signed char* r1q  = x0q  + (size_t)8192 * 2048;  // [8192][512]
    signed char* r0q  = r1q  + 8192 * 512;
    float* rF  = (float*)(r0q + 8192 * 512);         // [8192][512] fp32
    float* sa  = rF + (size_t)8192 * 512;            // [512]
    float* sat = sa  + 512;                          // [2048]
    float* sy  = sat + 2048;                         // [8192]
    float* sx  = sy  + 8192;                         // [8192]
    float* sr  = sx  + 8192;                         // [8192]

    rowquant_kernel<2048><<<128, 256, 0, stream>>>(A, A1q, A0q, sa);
    rowquant_kernel<512><<<512, 256, 0, stream>>>(W, AT1q, AT0q, sat);
    rowquant_kernel<512><<<2048, 256, 0, stream>>>(y, y1q, y0q, sy);

    // x0 = mu0 * y @ A  -> d_out fp32   (A-op = y planes, B-op = AT planes)
    gemm_i8<4, 0><<<dim3(16, 64), 256, 0, stream>>>(
        y1q, y0q, 512, AT1q, AT0q, 512, sy, sat,
        nullptr, out, mu, 0, 512, 2048);
    // quantize x0 for GEMM use (kSel=0: values unchanged, no fp32 rewrite)
    shrink_kernel<<<1024, 256, 0, stream>>>(out, x1q, x0q, sx, beta, 0, 0, 0, 1);

    for (int t = 1; t <= 5; ++t) {
        double p = 0.012 * t; if (p > 0.12) p = 0.12;
        int kSel = (int)(p * 2048.0);   // 24,49,73,98,122

        // r = x @ A^T - y  -> rF fp32   (A-op = x planes, B-op = A planes)
        gemm_i8<2, 1><<<dim3(8, 64), 256, 0, stream>>>(
            x1q, x0q, 2048, A1q, A0q, 2048, sx, sa,
            y, rF, mu, t, 2048, 512);
        // quantize r per-row
        rowquant_kernel<512><<<2048, 256, 0, stream>>>(rF, r1q, r0q, sr);

        // z = x - mu_t * (r @ A)  in place over d_out (x read fp32)
        gemm_i8<4, 2><<<dim3(16, 64), 256, 0, stream>>>(
            r1q, r0q, 512, AT1q, AT0q, 512, sr, sat,
            out, out, mu, t, 512, 2048);

        // x = shrink(z): fp32 in d_out (+ i8 planes unless last iteration)
        shrink_kernel<<<1024, 256, 0, stream>>>(out, x1q, x0q, sx, beta, t,
                                                kSel, 1, t < 5 ? 1 : 0);
    }
}

// Round 3
// 733.958 us; speedup vs baseline: 1.1865x; 1.1865x over previous
//
#include <hip/hip_runtime.h>

// ---------------------------------------------------------------------------
// TiLISTA: M=512, N=2048, B=8192, T=5 — i8 dual-plane GEMMs, fp32 x state.
//   x0 = mu0 * y @ A                      (fp32 in d_out)
//   for t=1..5:
//     r = x @ A^T - y        (fp32 in ws -> per-row i8 planes)
//     z = x - mu_t * (r @ A) (x read fp32 from d_out, z written in place)
//     x = shrink(z,beta,k)   (fp32 in d_out + i8 planes for next GEMM)
// GEMM operands: per-row q = q1*128 + q0 (|q|<=16256, ~15 bits of rowmax).
// 3 x mfma_i32_16x16x64_i8 per 64-K: a1b1->accH, a1b0+a0b1->accM;
// v = sA*sB*(accH*16384 + accM*128). Numerics: GEMM-input quant noise
// averages through A's unit-norm columns (~6e-6); x kept fp32 so direct
// storage error is 0. z error ~1e-5 = single tie-flip floor (R3-measured).
// Grid flat-swizzle: m-block = flat%64 -> same-m blocks share an XCD L2 (R6).
// R9: GEMM schedule rewrite (T2+T3+T4+T5): LDS double-buffer + prefetch-
//   before-compute, raw s_barrier + counted s_waitcnt vmcnt(L) (loads stay
//   in flight across barriers), XOR-swizzled tiles (source-side pre-swizzle,
//   read-side XOR), s_setprio around MFMA cluster. 72 -> <57 us per GEMM.
// R10 POST-MORTEM: 2-rows/wave shrink REGRESSED (57.6 -> 70.7 us): VGPR
//   52 -> 112 halved occupancy (33% -> 19%) on a latency-bound kernel.
//   Reverted to 1 row/wave.
// R11: shrink counting rewrite on the R9 structure:
//   - ballot counting: cnt += popcll(ballot(a[i] >= mid)) — 32 v_cmp/iter
//     (scalar-pipe popcount+add) replaces 32 cmp+addc (2x VALU) AND the
//     6-shfl butterfly (serial DS chain). Search state fully scalar.
//   - uniform early exit when cnt == kSel: any mid with cnt(>=mid)==k
//     classifies exactly the top-k set (== reference's a >= v_k); tie
//     straddling k makes cnt==k unreachable -> full search, same result.
//     Expected ~15-18 iters instead of 31. Bit-exact either way.
//   - t=5 skips plane+scale writes (nothing consumes them).
// shrink = exact k-th-largest |z| via binary search on float bits.
// ---------------------------------------------------------------------------

typedef int int4v __attribute__((ext_vector_type(4)));

__device__ __forceinline__ void quant2(float v, float inv_s,
                                       signed char& q1, signed char& q0) {
    int q = __float2int_rn(v * inv_s);
    q = q > 16256 ? 16256 : (q < -16256 ? -16256 : q);
    int hi = (q + 64) >> 7;            // round-half-up -> [-127,127]
    q1 = (signed char)hi;
    q0 = (signed char)(q - (hi << 7)); // [-64,63]
}

__device__ __forceinline__ void gl_lds16(const signed char* g, signed char* lds) {
    __builtin_amdgcn_global_load_lds(
        (const __attribute__((address_space(1))) void*)g,
        (__attribute__((address_space(3))) void*)lds, 16, 0, 0);
}

// out[m][n] = epilogue( sum_k Aop[m][k]*Bop[k][n] ); Bop in B^T layout [n][k].
// EPI 0: outF = mu * v                  (x0; A=y planes, B=AT planes)
// EPI 1: outF = v - yF                  (r;  A=x planes, B=A planes)
// EPI 2: outF = Yaux - mu * v, in place (z;  A=r planes, B=AT planes, Yaux=x)
template<int NJ, int EPI>
__global__ __launch_bounds__(256, 2) void gemm_i8(
    const signed char* __restrict__ A1, const signed char* __restrict__ A0, int lda,
    const signed char* __restrict__ B1, const signed char* __restrict__ B0, int ldb,
    const float* __restrict__ sAv,   // per-row scale of A-operand
    const float* __restrict__ sBv,   // per-row scale of B-operand (per out col)
    const float* __restrict__ Yaux,  // EPI1: y fp32 ; EPI2: x fp32 (= outF)
    float* __restrict__ outF,
    const float* __restrict__ muPtr, int muIdx, int K, int ldOut)
{
    constexpr int BN = 32 * NJ;      // 128 (NJ=4) or 64 (NJ=2)
    // double-buffered tiles: NJ=4 -> 64 KiB total, NJ=2 -> 48 KiB
    __shared__ signed char As1[2][128 * 64];
    __shared__ signed char As0[2][128 * 64];
    __shared__ signed char Bs1[2][BN * 64];
    __shared__ signed char Bs0[2][BN * 64];

    const int tid  = threadIdx.x;
    const int wid  = tid >> 6;
    const int lane = tid & 63;
    const int quad = lane >> 4;
    const int l16  = lane & 15;
    const int waveM = (wid >> 1) * 64;
    const int waveN = (wid & 1) * (16 * NJ);
    const int swz   = (l16 >> 1) & 3;          // read-side XOR (rows: base%16==0)

    const int flat  = blockIdx.x + gridDim.x * blockIdx.y;
    const int mBase = (flat & 63) * 128;
    const int nBase = (flat >> 6) * BN;

    int4v accH[4][NJ] = {};
    int4v accM[4][NJ] = {};

    // Stage one 64-K tile into buffer b. LDS dest linear (global_load_lds
    // requirement); the global SOURCE chunk is XOR-swizzled so that the
    // ds_read below, applying the same XOR, sees logical chunk order.
    auto stage = [&](int b, int k0) {
        #pragma unroll
        for (int rr = 0; rr < 2; ++rr) {
            int c   = rr * 256 + tid;          // 16B chunk id, 0..511
            int row = c >> 2;
            int js  = (c & 3) ^ ((row >> 1) & 3);
            size_t ga = (size_t)(mBase + row) * lda + k0 + js * 16;
            size_t doff = (size_t)((rr * 256 + wid * 64) * 16);
            gl_lds16(A1 + ga, As1[b] + doff);
            gl_lds16(A0 + ga, As0[b] + doff);
        }
        // chunk count = BN*64B / 16B = BN*4; iterations = BN*4/256 = BN/64
        #pragma unroll
        for (int rr = 0; rr < BN / 64; ++rr) {
            int c   = rr * 256 + tid;
            int row = c >> 2;
            int js  = (c & 3) ^ ((row >> 1) & 3);
            size_t gb = (size_t)(nBase + row) * ldb + k0 + js * 16;
            size_t doff = (size_t)((rr * 256 + wid * 64) * 16);
            gl_lds16(B1 + gb, Bs1[b] + doff);
            gl_lds16(B0 + gb, Bs0[b] + doff);
        }
    };

    const int KT = K >> 6;
    stage(0, 0);

    for (int kt = 0; kt < KT; ++kt) {
        const int cur = kt & 1;
        if (kt + 1 < KT) {
            stage(cur ^ 1, (kt + 1) << 6);
            // wait tile-kt's loads only; tile-(kt+1)'s L loads stay in flight
            if constexpr (NJ == 4) asm volatile("s_waitcnt vmcnt(8)" ::: "memory");
            else                   asm volatile("s_waitcnt vmcnt(6)" ::: "memory");
        } else {
            asm volatile("s_waitcnt vmcnt(0)" ::: "memory");
        }
        __builtin_amdgcn_s_barrier();          // raw: no vmcnt drain

        int4v a1[4], a0[4], b1[NJ], b0[NJ];
        #pragma unroll
        for (int i = 0; i < 4; ++i) {
            int off = (waveM + i * 16 + l16) * 64 + ((quad ^ swz) * 16);
            a1[i] = *(const int4v*)(&As1[cur][off]);
            a0[i] = *(const int4v*)(&As0[cur][off]);
        }
        #pragma unroll
        for (int j = 0; j < NJ; ++j) {
            int off = (waveN + j * 16 + l16) * 64 + ((quad ^ swz) * 16);
            b1[j] = *(const int4v*)(&Bs1[cur][off]);
            b0[j] = *(const int4v*)(&Bs0[cur][off]);
        }
        __builtin_amdgcn_s_setprio(1);
        #pragma unroll
        for (int i = 0; i < 4; ++i)
            #pragma unroll
            for (int j = 0; j < NJ; ++j) {
                accH[i][j] = __builtin_amdgcn_mfma_i32_16x16x64_i8(a1[i], b1[j], accH[i][j], 0, 0, 0);
                accM[i][j] = __builtin_amdgcn_mfma_i32_16x16x64_i8(a1[i], b0[j], accM[i][j], 0, 0, 0);
                accM[i][j] = __builtin_amdgcn_mfma_i32_16x16x64_i8(a0[i], b1[j], accM[i][j], 0, 0, 0);
            }
        __builtin_amdgcn_s_setprio(0);
        __builtin_amdgcn_s_barrier();          // reads of buf[cur] done before
                                               // next iter's stage overwrites it
    }

    const float mu = muPtr[muIdx];
    #pragma unroll
    for (int i = 0; i < 4; ++i) {
        #pragma unroll
        for (int j = 0; j < NJ; ++j) {
            const int gr0 = mBase + waveM + i * 16 + quad * 4;
            const int gc  = nBase + waveN + j * 16 + l16;
            const float sB = sBv[gc];
            #pragma unroll
            for (int r2 = 0; r2 < 4; ++r2) {
                const int    gr  = gr0 + r2;
                const size_t idx = (size_t)gr * ldOut + gc;
                const float  sA  = sAv[gr];
                float v = sA * sB * ((float)accH[i][j][r2] * 16384.f
                                   + (float)accM[i][j][r2] * 128.f);
                if constexpr (EPI == 0)      outF[idx] = mu * v;
                else if constexpr (EPI == 1) outF[idx] = v - Yaux[idx];
                else                         outF[idx] = Yaux[idx] - mu * v;
            }
        }
    }
}

// per-row quantization of a fp32 matrix to i8 dual planes + row scale
template<int COLS>
__global__ __launch_bounds__(256) void rowquant_kernel(
    const float* __restrict__ src,
    signed char* __restrict__ q1, signed char* __restrict__ q0,
    float* __restrict__ scale)
{
    const int wid  = threadIdx.x >> 6;
    const int lane = threadIdx.x & 63;
    const long long row = (long long)blockIdx.x * 4 + wid;
    constexpr int EP = COLS / 256;   // float4 per lane
    const float* s = src + row * COLS;

    float v[EP * 4];
    #pragma unroll
    for (int c = 0; c < EP; ++c) {
        float4 f = ((const float4*)s)[c * 64 + lane];
        v[c * 4 + 0] = f.x; v[c * 4 + 1] = f.y; v[c * 4 + 2] = f.z; v[c * 4 + 3] = f.w;
    }
    float mx = 0.f;
    #pragma unroll
    for (int i = 0; i < EP * 4; ++i) mx = fmaxf(mx, fabsf(v[i]));
    #pragma unroll
    for (int off = 32; off >= 1; off >>= 1) mx = fmaxf(mx, __shfl_xor(mx, off, 64));
    mx = fmaxf(mx, 1e-20f);
    if (lane == 0) scale[row] = mx / 16256.f;
    const float inv = 16256.f / mx;

    #pragma unroll
    for (int c = 0; c < EP; ++c) {
        size_t col = (size_t)(c * 64 + lane) * 4;
        signed char h[4], l[4];
        #pragma unroll
        for (int e = 0; e < 4; ++e) quant2(v[c * 4 + e], inv, h[e], l[e]);
        *(char4*)(q1 + row * COLS + col) = *(char4*)h;
        *(char4*)(q0 + row * COLS + col) = *(char4*)l;
    }
}

// R11: one wave per row of z[.,2048]: exact k-th-largest |z| hard/soft
// threshold via scalar binary search on float bits with ballot counting +
// uniform early exit; per-row quantize x -> i8 planes + scale, optionally
// write x fp32.
__global__ __launch_bounds__(256) void shrink_kernel(
    float* __restrict__ z,
    signed char* __restrict__ X1, signed char* __restrict__ X0,
    float* __restrict__ sX,
    const float* __restrict__ betaPtr, int tIdx, int kSel,
    int writeF32, int writePlanes)
{
    const int wid  = threadIdx.x >> 6;
    const int lane = threadIdx.x & 63;
    const long long row = (long long)blockIdx.x * 4 + wid;
    float* zr = z + row * 2048;

    float v[32];
    #pragma unroll
    for (int c = 0; c < 8; ++c) {
        float4 f = ((const float4*)zr)[c * 64 + lane];
        v[c * 4 + 0] = f.x; v[c * 4 + 1] = f.y; v[c * 4 + 2] = f.z; v[c * 4 + 3] = f.w;
    }

    if (kSel > 0) {
        const float beta = betaPtr[tIdx];
        unsigned a[32];
        #pragma unroll
        for (int i = 0; i < 32; ++i) a[i] = __float_as_uint(fabsf(v[i]));

        // invariant: cnt(>=lo) >= k, cnt(>=hi) < k. Early exit: any mid
        // with cnt(>=mid)==k classifies exactly the top-k set (identical
        // to thr = k-th largest); a tie straddling k makes cnt==k
        // unreachable -> loop runs to convergence (thr = v_k), also exact.
        unsigned lo = 0u, hi = 0x7F800000u;
        #pragma unroll 1
        for (int it = 0; it < 31; ++it) {
            const unsigned mid = (lo + hi) >> 1;
            int cnt = 0;
            #pragma unroll
            for (int i = 0; i < 32; ++i)
                cnt += (int)__popcll(__ballot(a[i] >= mid));
            if (cnt >= kSel) {
                lo = mid;
                if (cnt == kSel) break;
            } else {
                hi = mid;
            }
        }
        const unsigned thr = lo;
        #pragma unroll
        for (int i = 0; i < 32; ++i) {
            if (a[i] < thr) {
                float av   = __uint_as_float(a[i]);
                float soft = fmaxf(av - beta, 0.f);
                v[i] = copysignf(soft, v[i]);
            }
        }
    }

    float mx = 0.f;
    #pragma unroll
    for (int i = 0; i < 32; ++i) mx = fmaxf(mx, fabsf(v[i]));
    #pragma unroll
    for (int off = 32; off >= 1; off >>= 1) mx = fmaxf(mx, __shfl_xor(mx, off, 64));
    mx = fmaxf(mx, 1e-20f);
    if (writePlanes && lane == 0) sX[row] = mx / 16256.f;
    const float inv = 16256.f / mx;

    #pragma unroll
    for (int c = 0; c < 8; ++c) {
        size_t col = (size_t)(c * 64 + lane) * 4;
        if (writePlanes) {
            signed char h[4], l[4];
            #pragma unroll
            for (int e = 0; e < 4; ++e) quant2(v[c * 4 + e], inv, h[e], l[e]);
            *(char4*)(X1 + row * 2048 + col) = *(char4*)h;
            *(char4*)(X0 + row * 2048 + col) = *(char4*)l;
        }
        if (writeF32) {
            float4 f;
            f.x = v[c * 4 + 0]; f.y = v[c * 4 + 1]; f.z = v[c * 4 + 2]; f.w = v[c * 4 + 3];
            ((float4*)zr)[c * 64 + lane] = f;
        }
    }
}

extern "C" void kernel_launch(void* const* d_in, const int* in_sizes, int n_in,
                              void* d_out, int out_size, void* d_ws, size_t ws_size,
                              hipStream_t stream)
{
    const float* y    = (const float*)d_in[0];   // [8192,512]
    const float* A    = (const float*)d_in[1];   // [512,2048]
    const float* W    = (const float*)d_in[2];   // [2048,512] == A^T
    const float* beta = (const float*)d_in[3];   // [6]
    const float* mu   = (const float*)d_in[4];   // [6]
    float* out = (float*)d_out;                  // x / z fp32, in place

    // workspace (~68 MB)
    signed char* A1q  = (signed char*)d_ws;          // [512][2048]
    signed char* A0q  = A1q  + 512 * 2048;
    signed char* AT1q = A0q  + 512 * 2048;           // [2048][512]
    signed char* AT0q = AT1q + 2048 * 512;
    signed char* y1q  = AT0q + 2048 * 512;           // [8192][512]
    signed char* y0q  = y1q  + 8192 * 512;
    signed char* x1q  = y0q  + 8192 * 512;           // [8192][2048]
    signed char* x0q  = x1q  + (size_t)8192 * 2048;
    signed char* r1q  = x0q  + (size_t)8192 * 2048;  // [8192][512]
    signed char* r0q  = r1q  + 8192 * 512;
    float* rF  = (float*)(r0q + 8192 * 512);         // [8192][512] fp32
    float* sa  = rF + (size_t)8192 * 512;            // [512]
    float* sat = sa  + 512;                          // [2048]
    float* sy  = sat + 2048;                         // [8192]
    float* sx  = sy  + 8192;                         // [8192]
    float* sr  = sx  + 8192;                         // [8192]

    rowquant_kernel<2048><<<128, 256, 0, stream>>>(A, A1q, A0q, sa);
    rowquant_kernel<512><<<512, 256, 0, stream>>>(W, AT1q, AT0q, sat);
    rowquant_kernel<512><<<2048, 256, 0, stream>>>(y, y1q, y0q, sy);

    // x0 = mu0 * y @ A  -> d_out fp32   (A-op = y planes, B-op = AT planes)
    gemm_i8<4, 0><<<dim3(16, 64), 256, 0, stream>>>(
        y1q, y0q, 512, AT1q, AT0q, 512, sy, sat,
        nullptr, out, mu, 0, 512, 2048);
    // quantize x0 for GEMM use (kSel=0: values unchanged, no fp32 rewrite)
    shrink_kernel<<<2048, 256, 0, stream>>>(out, x1q, x0q, sx, beta, 0, 0, 0, 1);

    for (int t = 1; t <= 5; ++t) {
        double p = 0.012 * t; if (p > 0.12) p = 0.12;
        int kSel = (int)(p * 2048.0);   // 24,49,73,98,122

        // r = x @ A^T - y  -> rF fp32   (A-op = x planes, B-op = A planes)
        gemm_i8<2, 1><<<dim3(8, 64), 256, 0, stream>>>(
            x1q, x0q, 2048, A1q, A0q, 2048, sx, sa,
            y, rF, mu, t, 2048, 512);
        // quantize r per-row
        rowquant_kernel<512><<<2048, 256, 0, stream>>>(rF, r1q, r0q, sr);

        // z = x - mu_t * (r @ A)  in place over d_out (x read fp32)
        gemm_i8<4, 2><<<dim3(16, 64), 256, 0, stream>>>(
            r1q, r0q, 512, AT1q, AT0q, 512, sr, sat,
            out, out, mu, t, 512, 2048);

        // x = shrink(z): fp32 in d_out (+ i8 planes unless last iteration)
        shrink_kernel<<<2048, 256, 0, stream>>>(out, x1q, x0q, sx, beta, t,
                                                kSel, 1, t < 5 ? 1 : 0);
    }
}